// Round 5
// baseline (379.661 us; speedup 1.0000x reference)
//
#include <hip/hip_runtime.h>
#include <hip/hip_bf16.h>

// ---------------------------------------------------------------------------
// Transformer block: x + attn(LN1(x)) ; then x2 + proj(relu(fc(LN2(x2))))
// B=2, T=2048, C=1024, H=16, hd=64, MLP hidden 4096. All GEMMs bf16 MFMA.
// R5: GEMMs switch from global_load_lds (vmcnt(0)-drained at each barrier,
//     zero overlap) to register-prefetch pipeline (the structure that fixed
//     attention in R4): next tile's global loads issue after the 2nd barrier
//     and complete during MFMA. LDS rows padded to 40 elems (80B) -> frag
//     reads/writes drop from 8-way to <=2-way bank aliasing.
// ---------------------------------------------------------------------------

typedef __bf16  bf16x8  __attribute__((ext_vector_type(8)));
typedef float   floatx4 __attribute__((ext_vector_type(4)));

#define T_LEN 2048
#define EMB   1024
#define NH    16
#define HD    64
#define HID   4096

// ---------------- transpose + cast: in fp32 [R,C] -> out bf16 [C,R] --------
__global__ void transpose_cast(const float* __restrict__ in,
                               __bf16* __restrict__ out, int R, int C) {
    __shared__ float tile[32][33];
    int bc = blockIdx.x * 32;
    int br = blockIdx.y * 32;
    int tx = threadIdx.x;
    int ty = threadIdx.y;
    for (int i = 0; i < 32; i += 8) {
        tile[ty + i][tx] = in[(size_t)(br + ty + i) * C + bc + tx];
    }
    __syncthreads();
    for (int i = 0; i < 32; i += 8) {
        int c = bc + ty + i, r = br + tx;
        out[(size_t)c * R + r] = (__bf16)tile[tx][ty + i];
    }
}

// ---------------- layernorm fp32 [M,1024] -> bf16 [M,1024] -----------------
__global__ __launch_bounds__(256)
void ln_kernel(const float* __restrict__ in, const float* __restrict__ sc,
               const float* __restrict__ sh, __bf16* __restrict__ out) {
    int row = blockIdx.x;
    const float* p = in + (size_t)row * EMB;
    int tid = threadIdx.x;
    int lane = tid & 63, wave = tid >> 6;
    float v[4];
    float s = 0.f, s2 = 0.f;
    for (int j = 0; j < 4; j++) {
        v[j] = p[tid + j * 256];
        s += v[j]; s2 += v[j] * v[j];
    }
    for (int m = 1; m < 64; m <<= 1) {
        s  += __shfl_xor(s, m);
        s2 += __shfl_xor(s2, m);
    }
    __shared__ float ssum[4], ssum2[4];
    if (lane == 0) { ssum[wave] = s; ssum2[wave] = s2; }
    __syncthreads();
    float tot  = ssum[0] + ssum[1] + ssum[2] + ssum[3];
    float tot2 = ssum2[0] + ssum2[1] + ssum2[2] + ssum2[3];
    float mean = tot * (1.f / EMB);
    float var  = tot2 * (1.f / EMB) - mean * mean;
    float rstd = rsqrtf(var + 1e-5f);
    for (int j = 0; j < 4; j++) {
        int c = tid + j * 256;
        out[(size_t)row * EMB + c] = (__bf16)((v[j] - mean) * rstd * sc[c] + sh[c]);
    }
}

// ---------------- bf16 MFMA GEMM (BM=128, BN=128), reg-prefetch pipeline ---
__global__ __launch_bounds__(256)
void gemm_bt(const __bf16* __restrict__ A, const __bf16* __restrict__ Bt,
             const float* __restrict__ bias, const float* __restrict__ res,
             float* __restrict__ outF, __bf16* __restrict__ outB,
             int M, int N, int K, int relu) {
    __shared__ __align__(16) __bf16 sA[128][40];   // 80B rows: <=2-way banks
    __shared__ __align__(16) __bf16 sB[128][40];
    int tid  = threadIdx.x;
    int lane = tid & 63, wave = tid >> 6;
    int quad = lane >> 4, l16 = lane & 15;
    int bm = blockIdx.y * 128, bn = blockIdx.x * 128;
    int wm = (wave & 1) * 64, wn = (wave >> 1) * 64;
    floatx4 acc[4][4] = {};

    int srow = tid >> 2;          // 0..63
    int scol = (tid & 3) * 8;     // 0,8,16,24
    const __bf16* gA = &A[(size_t)(bm + srow) * K + scol];
    const __bf16* gB = &Bt[(size_t)(bn + srow) * K + scol];

    // prologue: tile 0 into registers
    uint4 ra0 = *(const uint4*)gA;
    uint4 ra1 = *(const uint4*)(gA + (size_t)64 * K);
    uint4 rb0 = *(const uint4*)gB;
    uint4 rb1 = *(const uint4*)(gB + (size_t)64 * K);

    for (int kk = 0; kk < K; kk += 32) {
        __syncthreads();                    // readers done with prev tile
        *(uint4*)&sA[srow][scol]      = ra0;
        *(uint4*)&sA[srow + 64][scol] = ra1;
        *(uint4*)&sB[srow][scol]      = rb0;
        *(uint4*)&sB[srow + 64][scol] = rb1;
        __syncthreads();
        // prefetch next tile into regs: no vmcnt drain at barriers, the
        // loads complete during the MFMA block below.
        {
            int kn = (kk + 32 < K) ? kk + 32 : kk;
            ra0 = *(const uint4*)(gA + kn);
            ra1 = *(const uint4*)(gA + kn + (size_t)64 * K);
            rb0 = *(const uint4*)(gB + kn);
            rb1 = *(const uint4*)(gB + kn + (size_t)64 * K);
        }
        bf16x8 af[4], bfr[4];
        for (int i = 0; i < 4; i++)
            af[i] = *(const bf16x8*)&sA[wm + i * 16 + l16][quad * 8];
        for (int j = 0; j < 4; j++)
            bfr[j] = *(const bf16x8*)&sB[wn + j * 16 + l16][quad * 8];
        for (int i = 0; i < 4; i++)
            for (int j = 0; j < 4; j++)
                acc[i][j] = __builtin_amdgcn_mfma_f32_16x16x32_bf16(
                    af[i], bfr[j], acc[i][j], 0, 0, 0);
    }

    for (int i = 0; i < 4; i++) {
        int row0 = bm + wm + i * 16 + quad * 4;
        for (int j = 0; j < 4; j++) {
            int col = bn + wn + j * 16 + l16;
            float bv = bias[col];
            for (int r = 0; r < 4; r++) {
                size_t idx = (size_t)(row0 + r) * N + col;
                float c = acc[i][j][r] + bv;
                if (relu) c = fmaxf(c, 0.f);
                if (res)  c += res[idx];
                if (outF) outF[idx] = c;
                if (outB) outB[idx] = (__bf16)c;
            }
        }
    }
}

// ---------------- bf16 MFMA GEMM (BM=128, BN=64), reg-prefetch pipeline ----
__global__ __launch_bounds__(256)
void gemm_bt_n64(const __bf16* __restrict__ A, const __bf16* __restrict__ Bt,
                 const float* __restrict__ bias, const float* __restrict__ res,
                 float* __restrict__ outF, __bf16* __restrict__ outB,
                 int M, int N, int K, int relu) {
    __shared__ __align__(16) __bf16 sA[128][40];
    __shared__ __align__(16) __bf16 sB[64][40];
    int tid  = threadIdx.x;
    int lane = tid & 63, wave = tid >> 6;
    int quad = lane >> 4, l16 = lane & 15;
    int bm = blockIdx.y * 128, bn = blockIdx.x * 64;
    int wm = (wave & 1) * 64, wn = (wave >> 1) * 32;
    floatx4 acc[4][2] = {};

    int srow = tid >> 2;          // 0..63
    int scol = (tid & 3) * 8;
    const __bf16* gA = &A[(size_t)(bm + srow) * K + scol];
    const __bf16* gB = &Bt[(size_t)(bn + srow) * K + scol];

    uint4 ra0 = *(const uint4*)gA;
    uint4 ra1 = *(const uint4*)(gA + (size_t)64 * K);
    uint4 rb0 = *(const uint4*)gB;

    for (int kk = 0; kk < K; kk += 32) {
        __syncthreads();
        *(uint4*)&sA[srow][scol]      = ra0;
        *(uint4*)&sA[srow + 64][scol] = ra1;
        *(uint4*)&sB[srow][scol]      = rb0;
        __syncthreads();
        {
            int kn = (kk + 32 < K) ? kk + 32 : kk;
            ra0 = *(const uint4*)(gA + kn);
            ra1 = *(const uint4*)(gA + kn + (size_t)64 * K);
            rb0 = *(const uint4*)(gB + kn);
        }
        bf16x8 af[4], bfr[2];
        for (int i = 0; i < 4; i++)
            af[i] = *(const bf16x8*)&sA[wm + i * 16 + l16][quad * 8];
        for (int j = 0; j < 2; j++)
            bfr[j] = *(const bf16x8*)&sB[wn + j * 16 + l16][quad * 8];
        for (int i = 0; i < 4; i++)
            for (int j = 0; j < 2; j++)
                acc[i][j] = __builtin_amdgcn_mfma_f32_16x16x32_bf16(
                    af[i], bfr[j], acc[i][j], 0, 0, 0);
    }

    for (int i = 0; i < 4; i++) {
        int row0 = bm + wm + i * 16 + quad * 4;
        for (int j = 0; j < 2; j++) {
            int col = bn + wn + j * 16 + l16;
            float bv = bias[col];
            for (int r = 0; r < 4; r++) {
                size_t idx = (size_t)(row0 + r) * N + col;
                float c = acc[i][j][r] + bv;
                if (relu) c = fmaxf(c, 0.f);
                if (res)  c += res[idx];
                if (outF) outF[idx] = c;
                if (outB) outB[idx] = (__bf16)c;
            }
        }
    }
}

// ---------------- flash attention (unchanged from R4) ----------------------
__global__ __launch_bounds__(256)
void attn_kernel(const __bf16* __restrict__ qkv, const float* __restrict__ x,
                 float* __restrict__ x2) {
    __shared__ __align__(16) __bf16 sK[64][72];
    __shared__ __align__(16) __bf16 sVt[64][72];
    __shared__ __align__(16) __bf16 sP[4][16][72];
    const int tid  = threadIdx.x;
    const int lane = tid & 63, wave = tid >> 6;
    const int quad = lane >> 4, l16 = lane & 15;
    const int xpair = blockIdx.x;         // 0..15
    const int bh = blockIdx.y;
    const int h  = bh & (NH - 1);
    const int b  = bh >> 4;
    const size_t rowbase = (size_t)b * T_LEN;

    const float kQScale = 0.125f * 1.44269504088896f;
    bf16x8 ones;
    for (int j = 0; j < 8; j++) ones[j] = (__bf16)1.0f;

    const int key0 = tid >> 3, m8 = tid & 7;
    const int key1 = key0 + 32;
    const __bf16* kp0 = qkv + (rowbase + key0) * 3072 + h * HD + m8 * 8 + 1024;
    const __bf16* kp1 = qkv + (rowbase + key1) * 3072 + h * HD + m8 * 8 + 1024;
    const int pc0 = ((key0 >> 3) ^ m8) * 8 + (key0 & 7);
    const int pc1 = ((key1 >> 3) ^ m8) * 8 + (key1 & 7);

    for (int ph = 0; ph < 2; ph++) {
        const int qb = ph ? (31 - xpair) : xpair;
        const int qrow = qb * 64 + wave * 16;

        bf16x8 qf[2];
        for (int ks = 0; ks < 2; ks++) {
            bf16x8 raw = *(const bf16x8*)&qkv[(rowbase + qrow + l16) * 3072
                                              + h * HD + ks * 32 + quad * 8];
            for (int j = 0; j < 8; j++)
                qf[ks][j] = (__bf16)((float)raw[j] * kQScale);
        }

        floatx4 o[4] = {}, ol = {};
        float mrow[4];
        for (int r = 0; r < 4; r++) mrow[r] = -1e30f;

        uint4 kr0 = *(const uint4*)kp0;
        uint4 kr1 = *(const uint4*)kp1;
        uint4 vr0 = *(const uint4*)(kp0 + 1024);
        uint4 vr1 = *(const uint4*)(kp1 + 1024);

        const int ntiles = qb + 1;
        for (int kt = 0; kt < ntiles; kt++) {
            __syncthreads();
            *(uint4*)&sK[key0][m8 * 8] = kr0;
            *(uint4*)&sK[key1][m8 * 8] = kr1;
            {
                bf16x8 v0 = *(bf16x8*)&vr0, v1 = *(bf16x8*)&vr1;
                for (int j = 0; j < 8; j++) sVt[m8 * 8 + j][pc0] = v0[j];
                for (int j = 0; j < 8; j++) sVt[m8 * 8 + j][pc1] = v1[j];
            }
            __syncthreads();

            {
                size_t offn = (size_t)((kt + 1 < ntiles) ? kt + 1 : kt)
                              * (64 * 3072);
                kr0 = *(const uint4*)(kp0 + offn);
                kr1 = *(const uint4*)(kp1 + offn);
                vr0 = *(const uint4*)(kp0 + offn + 1024);
                vr1 = *(const uint4*)(kp1 + offn + 1024);
            }

            floatx4 s_acc[4] = {};
            for (int jt = 0; jt < 4; jt++)
                for (int ks = 0; ks < 2; ks++) {
                    bf16x8 kf = *(const bf16x8*)&sK[jt * 16 + l16]
                                                  [ks * 32 + quad * 8];
                    s_acc[jt] = __builtin_amdgcn_mfma_f32_16x16x32_bf16(
                        qf[ks], kf, s_acc[jt], 0, 0, 0);
                }

            const int tq0 = qrow + quad * 4;
            const int k0 = kt * 64;
            float rmax[4] = {-1e30f, -1e30f, -1e30f, -1e30f};
            if (kt == qb) {
                for (int jt = 0; jt < 4; jt++) {
                    int key = k0 + jt * 16 + l16;
                    for (int r = 0; r < 4; r++) {
                        float sv = (key <= tq0 + r) ? s_acc[jt][r] : -1e30f;
                        s_acc[jt][r] = sv;
                        rmax[r] = fmaxf(rmax[r], sv);
                    }
                }
            } else {
                for (int jt = 0; jt < 4; jt++)
                    for (int r = 0; r < 4; r++)
                        rmax[r] = fmaxf(rmax[r], s_acc[jt][r]);
            }

            bool changed = false;
            float mnew[4];
            for (int r = 0; r < 4; r++) {
                float m = rmax[r];
                m = fmaxf(m, __shfl_xor(m, 1));
                m = fmaxf(m, __shfl_xor(m, 2));
                m = fmaxf(m, __shfl_xor(m, 4));
                m = fmaxf(m, __shfl_xor(m, 8));
                mnew[r] = fmaxf(mrow[r], m);
                changed |= (mnew[r] > mrow[r]);
            }
            if (__any(changed)) {
                for (int r = 0; r < 4; r++) {
                    float alpha = __builtin_amdgcn_exp2f(mrow[r] - mnew[r]);
                    mrow[r] = mnew[r];
                    ol[r] *= alpha;
                    for (int jt = 0; jt < 4; jt++) o[jt][r] *= alpha;
                }
            }

            for (int jt = 0; jt < 4; jt++)
                for (int r = 0; r < 4; r++) {
                    float pv = __builtin_amdgcn_exp2f(s_acc[jt][r] - mrow[r]);
                    sP[wave][quad * 4 + r][jt * 16 + l16] = (__bf16)pv;
                }

            for (int kp = 0; kp < 2; kp++) {
                bf16x8 pf = *(const bf16x8*)&sP[wave][l16][kp * 32 + quad * 8];
                ol = __builtin_amdgcn_mfma_f32_16x16x32_bf16(pf, ones, ol,
                                                             0, 0, 0);
                for (int jt2 = 0; jt2 < 4; jt2++) {
                    int d = jt2 * 16 + l16;
                    int pg = (kp * 4 + quad) ^ (d >> 3);
                    bf16x8 vf = *(const bf16x8*)&sVt[d][pg * 8];
                    o[jt2] = __builtin_amdgcn_mfma_f32_16x16x32_bf16(
                        pf, vf, o[jt2], 0, 0, 0);
                }
            }
        }

        float inv[4];
        for (int r = 0; r < 4; r++) inv[r] = __builtin_amdgcn_rcpf(ol[r]);
        for (int jt2 = 0; jt2 < 4; jt2++) {
            for (int r = 0; r < 4; r++) {
                int tq  = qrow + quad * 4 + r;
                int col = h * HD + jt2 * 16 + l16;
                size_t gi = (rowbase + tq) * EMB + col;
                x2[gi] = x[gi] + o[jt2][r] * inv[r];
            }
        }
    }
}

// ---------------------------------------------------------------------------
extern "C" void kernel_launch(void* const* d_in, const int* in_sizes, int n_in,
                              void* d_out, int out_size, void* d_ws, size_t ws_size,
                              hipStream_t stream) {
    const float* x      = (const float*)d_in[0];
    const float* ln1_s  = (const float*)d_in[1];
    const float* ln1_b  = (const float*)d_in[2];
    const float* w_qkv  = (const float*)d_in[3];
    const float* b_qkv  = (const float*)d_in[4];
    const float* ln2_s  = (const float*)d_in[5];
    const float* ln2_b  = (const float*)d_in[6];
    const float* w_fc   = (const float*)d_in[7];
    const float* b_fc   = (const float*)d_in[8];
    const float* w_proj = (const float*)d_in[9];
    const float* b_proj = (const float*)d_in[10];
    float* out = (float*)d_out;

    const int M = 2 * T_LEN;  // 4096 rows
    char* ws = (char*)d_ws;
    size_t off = 0;
    auto alloc = [&](size_t bytes) {
        void* p = ws + off; off += (bytes + 255) & ~(size_t)255; return p;
    };
    __bf16* wqkv_t = (__bf16*)alloc((size_t)3072 * 1024 * 2);
    __bf16* wfc_t  = (__bf16*)alloc((size_t)4096 * 1024 * 2);
    __bf16* wpj_t  = (__bf16*)alloc((size_t)1024 * 4096 * 2);
    __bf16* h1     = (__bf16*)alloc((size_t)M * 1024 * 2);
    __bf16* qkvb   = (__bf16*)alloc((size_t)M * 3072 * 2);
    float*  x2     = (float*) alloc((size_t)M * 1024 * 4);
    __bf16* h2     = (__bf16*)alloc((size_t)M * 1024 * 2);
    __bf16* hfc    = (__bf16*)alloc((size_t)M * 4096 * 2);

    dim3 tb(32, 8);
    transpose_cast<<<dim3(3072 / 32, 1024 / 32), tb, 0, stream>>>(w_qkv, wqkv_t, 1024, 3072);
    transpose_cast<<<dim3(4096 / 32, 1024 / 32), tb, 0, stream>>>(w_fc,  wfc_t,  1024, 4096);
    transpose_cast<<<dim3(1024 / 32, 4096 / 32), tb, 0, stream>>>(w_proj, wpj_t, 4096, 1024);

    ln_kernel<<<M, 256, 0, stream>>>(x, ln1_s, ln1_b, h1);

    gemm_bt<<<dim3(3072 / 128, M / 128), 256, 0, stream>>>(
        h1, wqkv_t, b_qkv, nullptr, nullptr, qkvb, M, 3072, 1024, 0);

    attn_kernel<<<dim3(16, 2 * NH), 256, 0, stream>>>(qkvb, x, x2);

    ln_kernel<<<M, 256, 0, stream>>>(x2, ln2_s, ln2_b, h2);

    gemm_bt<<<dim3(4096 / 128, M / 128), 256, 0, stream>>>(
        h2, wfc_t, b_fc, nullptr, nullptr, hfc, M, 4096, 1024, 1);

    gemm_bt_n64<<<dim3(1024 / 64, M / 128), 256, 0, stream>>>(
        hfc, wpj_t, b_proj, x2, out, nullptr, M, 1024, 4096, 0);
}